// Round 7
// baseline (18631.085 us; speedup 1.0000x reference)
//
#include <hip/hip_runtime.h>
#include <hip/hip_bf16.h>
#include <stdint.h>
#include <stddef.h>

// STNRNN round 6 (resubmit; bench lost to GPU-broker timeout twice).
// r3's proven MFMA data path (passed, absmax 3.9e-3) with the barrier
// replaced by a wait-free per-wave flag protocol, 4-way MFMA ILP, and
// x-part hoisted before the wait.
//
// Sync protocol (no atomics, no __syncthreads, no s_barrier):
//   producer wave: state stores (sc0sc1) -> s_waitcnt vmcnt(0) (stores acked
//   at MALL) -> store flags[g][wave] = t+1 (sc0sc1, fire-and-forget).
//   consumer wave at step t>=1: poll 64 group flags (16x dwordx4 sc0sc1)
//   until min >= t, then issue state loads. Flag visible => state visible,
//   because the flag store is issued only after state stores are acked at
//   the coherence point. Flags are monotonic (no reset/reuse races); ws is
//   memset 0 each launch (h0 = 0 and flags = 0).

#define T_STEPS 2048
#define H_DIM   512
#define I_DIM   64
#define B_TOT   32
#define NGROUP  16
#define WGS     16
#define BPG     2
#define NTH     256

typedef float f32x4 __attribute__((ext_vector_type(4)));
typedef short s16x8 __attribute__((ext_vector_type(8)));

#define STATE_HALF (B_TOT*H_DIM)                  // ushorts per slot
#define SHI_BYTES  (2*STATE_HALF*2)               // 65536 (double buffered)
#define SRES_OFF   SHI_BYTES
#define FLAGS_OFF  (2*SHI_BYTES)                  // 131072
#define WS_BYTES   (FLAGS_OFF + NGROUP*64*4)      // +4096 = 135168

__device__ __forceinline__ unsigned short bf16_rne(float f) {
  __hip_bfloat16 b = __float2bfloat16(f);
  return __builtin_bit_cast(unsigned short, b);
}
__device__ __forceinline__ float bf16_to_f(unsigned short u) {
  return __uint_as_float(((unsigned)u) << 16);
}
__device__ __forceinline__ f32x4 ld_mall_b128(const void* p) {
  f32x4 r;
  asm volatile("global_load_dwordx4 %0, %1, off sc0 sc1" : "=v"(r) : "v"(p));
  return r;
}
__device__ __forceinline__ uint4 ld_mall_u4(const void* p) {
  uint4 r;
  asm volatile("global_load_dwordx4 %0, %1, off sc0 sc1" : "=v"(r) : "v"(p));
  return r;
}
__device__ __forceinline__ void st_mall_u16(void* p, unsigned v) {
  asm volatile("global_store_short %0, %1, off sc0 sc1" :: "v"(p), "v"(v) : "memory");
}
__device__ __forceinline__ void st_mall_b32(void* p, unsigned v) {
  asm volatile("global_store_dword %0, %1, off sc0 sc1" :: "v"(p), "v"(v) : "memory");
}
__device__ __forceinline__ s16x8 make_frag(const float* p) {
  const float4 a = *(const float4*)p;
  const float4 b = *(const float4*)(p + 4);
  s16x8 f;
  f[0] = (short)bf16_rne(a.x); f[1] = (short)bf16_rne(a.y);
  f[2] = (short)bf16_rne(a.z); f[3] = (short)bf16_rne(a.w);
  f[4] = (short)bf16_rne(b.x); f[5] = (short)bf16_rne(b.y);
  f[6] = (short)bf16_rne(b.z); f[7] = (short)bf16_rne(b.w);
  return f;
}
__device__ __forceinline__ void split8(const float4& a, const float4& b,
                                       s16x8& hi, s16x8& lo) {
  float v[8] = {a.x, a.y, a.z, a.w, b.x, b.y, b.z, b.w};
  #pragma unroll
  for (int e = 0; e < 8; ++e) {
    const unsigned short h = bf16_rne(v[e]);
    hi[e] = (short)h;
    lo[e] = (short)bf16_rne(v[e] - bf16_to_f(h));
  }
}
__device__ __forceinline__ float sigmoid_f(float v) { return 1.0f / (1.0f + __expf(-v)); }
__device__ __forceinline__ float tanh_f(float v)    { return 1.0f - 2.0f / (1.0f + __expf(2.0f * v)); }

extern "C" __global__ void __launch_bounds__(NTH, 1)
stnrnn_kernel(const float* __restrict__ x,
              const float* __restrict__ Wih,
              const float* __restrict__ Whh,
              const float* __restrict__ bih,
              const float* __restrict__ bhh,
              float* __restrict__ out,
              unsigned short* sHi,   // ws: [2][B_TOT][H_DIM] bf16 hi
              unsigned short* sRes,  // ws: [2][B_TOT][H_DIM] bf16 residual
              unsigned* flags)       // ws: [NGROUP][64] per-wave step count
{
  const int bid = blockIdx.x;
  const int g   = bid & 15;
  const int m   = bid >> 4;
  const int tid = threadIdx.x;
  const int w   = tid >> 6;
  const int l   = tid & 63;
  const int p   = l >> 4;
  const int c16 = l & 15;
  const int bb  = c16 & 1;
  const int bg0 = g * BPG;
  const int jj  = c16 >> 2, q = c16 & 3;

  // ---- one-time A fragments (W in VGPRs/AGPRs, bf16) — r3-identical ----
  s16x8 ahh[2][16];
  s16x8 aih[2][2];
  #pragma unroll
  for (int rt = 0; rt < 2; ++rt) {
    const int jbase = m * 32 + (w * 2 + rt) * 4;
    const int grow  = q * H_DIM + jbase + jj;
    #pragma unroll
    for (int kt = 0; kt < 16; ++kt)
      ahh[rt][kt] = make_frag(Whh + (size_t)grow * H_DIM + kt * 32 + p * 8);
    #pragma unroll
    for (int kt = 0; kt < 2; ++kt)
      aih[rt][kt] = make_frag(Wih + (size_t)grow * I_DIM + kt * 32 + p * 8);
  }
  float bias[2][4];
  #pragma unroll
  for (int rt = 0; rt < 2; ++rt) {
    const int jx = m * 32 + (w * 2 + rt) * 4 + p;
    #pragma unroll
    for (int qq = 0; qq < 4; ++qq)
      bias[rt][qq] = bih[qq * H_DIM + jx] + bhh[qq * H_DIM + jx];
  }
  const int  jme[2] = {m * 32 + (w * 2) * 4 + p, m * 32 + (w * 2 + 1) * 4 + p};
  const int  bme    = bg0 + c16;
  const bool active = (c16 < BPG);

  float hreg[2] = {0.f, 0.f}, creg[2] = {0.f, 0.f};
  const unsigned* const gflags = flags + g * 64;
  unsigned* const myflag = flags + g * 64 + m * 4 + w;

  for (int t = 0; t < T_STEPS; ++t) {
    const unsigned short* hiB = sHi  + (size_t)(t & 1) * STATE_HALF;
    const unsigned short* reB = sRes + (size_t)(t & 1) * STATE_HALF;
    unsigned short* oHiBase = sHi  + (size_t)((t + 1) & 1) * STATE_HALF;
    unsigned short* oReBase = sRes + (size_t)((t + 1) & 1) * STATE_HALF;

    f32x4 a0 = {0.f,0.f,0.f,0.f}, a1 = {0.f,0.f,0.f,0.f};
    f32x4 a2 = {0.f,0.f,0.f,0.f}, a3 = {0.f,0.f,0.f,0.f};

    // ---- x part first (plain cached loads; hides the flag poll) ----
    {
      const float* xp = x + ((size_t)(bg0 + bb) * T_STEPS + t) * I_DIM + p * 8;
      const float4 xv0a = *(const float4*)(xp);
      const float4 xv0b = *(const float4*)(xp + 4);
      const float4 xv1a = *(const float4*)(xp + 32);
      const float4 xv1b = *(const float4*)(xp + 36);
      s16x8 xh0, xr0, xh1, xr1;
      split8(xv0a, xv0b, xh0, xr0);
      split8(xv1a, xv1b, xh1, xr1);
      a0 = __builtin_amdgcn_mfma_f32_16x16x32_bf16(aih[0][0], xh0, a0, 0, 0, 0);
      a0 = __builtin_amdgcn_mfma_f32_16x16x32_bf16(aih[0][0], xr0, a0, 0, 0, 0);
      a2 = __builtin_amdgcn_mfma_f32_16x16x32_bf16(aih[1][0], xh0, a2, 0, 0, 0);
      a2 = __builtin_amdgcn_mfma_f32_16x16x32_bf16(aih[1][0], xr0, a2, 0, 0, 0);
      a1 = __builtin_amdgcn_mfma_f32_16x16x32_bf16(aih[0][1], xh1, a1, 0, 0, 0);
      a1 = __builtin_amdgcn_mfma_f32_16x16x32_bf16(aih[0][1], xr1, a1, 0, 0, 0);
      a3 = __builtin_amdgcn_mfma_f32_16x16x32_bf16(aih[1][1], xh1, a3, 0, 0, 0);
      a3 = __builtin_amdgcn_mfma_f32_16x16x32_bf16(aih[1][1], xr1, a3, 0, 0, 0);
    }

    // ---- wait-free flag poll: all 64 group waves finished step t-1 ----
    if (t > 0) {
      const unsigned tgt = (unsigned)t;
      for (;;) {
        uint4 f[16];
        #pragma unroll
        for (int i = 0; i < 16; ++i) f[i] = ld_mall_u4(gflags + i * 4);
        asm volatile("s_waitcnt vmcnt(0)" ::: "memory");
        __builtin_amdgcn_sched_barrier(0);
        unsigned mn = 0xffffffffu;
        #pragma unroll
        for (int i = 0; i < 16; ++i) {
          mn = f[i].x < mn ? f[i].x : mn;
          mn = f[i].y < mn ? f[i].y : mn;
          mn = f[i].z < mn ? f[i].z : mn;
          mn = f[i].w < mn ? f[i].w : mn;
        }
        if (mn >= tgt) break;
        __builtin_amdgcn_s_sleep(1);
      }
      __builtin_amdgcn_sched_barrier(0);
    }

    // ---- issue all 32 state loads (MALL-coherent), two-phase consume ----
    const size_t bOff = (size_t)(bg0 + bb) * H_DIM + p * 8;
    f32x4 bhi[16], bres[16];
    #pragma unroll
    for (int kt = 0; kt < 16; ++kt) {
      bhi[kt]  = ld_mall_b128(hiB + bOff + kt * 32);
      bres[kt] = ld_mall_b128(reB + bOff + kt * 32);
    }

    // phase 1: oldest 16 loads (kt 0..7 hi+res) complete at vmcnt(16)
    asm volatile("s_waitcnt vmcnt(16)" ::: "memory");
    __builtin_amdgcn_sched_barrier(0);
    #pragma unroll
    for (int kt = 0; kt < 8; kt += 2) {
      const s16x8 vh = __builtin_bit_cast(s16x8, bhi[kt]);
      const s16x8 vr = __builtin_bit_cast(s16x8, bres[kt]);
      a0 = __builtin_amdgcn_mfma_f32_16x16x32_bf16(ahh[0][kt], vh, a0, 0, 0, 0);
      a0 = __builtin_amdgcn_mfma_f32_16x16x32_bf16(ahh[0][kt], vr, a0, 0, 0, 0);
      a2 = __builtin_amdgcn_mfma_f32_16x16x32_bf16(ahh[1][kt], vh, a2, 0, 0, 0);
      a2 = __builtin_amdgcn_mfma_f32_16x16x32_bf16(ahh[1][kt], vr, a2, 0, 0, 0);
      const s16x8 wh = __builtin_bit_cast(s16x8, bhi[kt + 1]);
      const s16x8 wr = __builtin_bit_cast(s16x8, bres[kt + 1]);
      a1 = __builtin_amdgcn_mfma_f32_16x16x32_bf16(ahh[0][kt + 1], wh, a1, 0, 0, 0);
      a1 = __builtin_amdgcn_mfma_f32_16x16x32_bf16(ahh[0][kt + 1], wr, a1, 0, 0, 0);
      a3 = __builtin_amdgcn_mfma_f32_16x16x32_bf16(ahh[1][kt + 1], wh, a3, 0, 0, 0);
      a3 = __builtin_amdgcn_mfma_f32_16x16x32_bf16(ahh[1][kt + 1], wr, a3, 0, 0, 0);
    }
    // phase 2: everything done
    asm volatile("s_waitcnt vmcnt(0)" ::: "memory");
    __builtin_amdgcn_sched_barrier(0);
    #pragma unroll
    for (int kt = 8; kt < 16; kt += 2) {
      const s16x8 vh = __builtin_bit_cast(s16x8, bhi[kt]);
      const s16x8 vr = __builtin_bit_cast(s16x8, bres[kt]);
      a0 = __builtin_amdgcn_mfma_f32_16x16x32_bf16(ahh[0][kt], vh, a0, 0, 0, 0);
      a0 = __builtin_amdgcn_mfma_f32_16x16x32_bf16(ahh[0][kt], vr, a0, 0, 0, 0);
      a2 = __builtin_amdgcn_mfma_f32_16x16x32_bf16(ahh[1][kt], vh, a2, 0, 0, 0);
      a2 = __builtin_amdgcn_mfma_f32_16x16x32_bf16(ahh[1][kt], vr, a2, 0, 0, 0);
      const s16x8 wh = __builtin_bit_cast(s16x8, bhi[kt + 1]);
      const s16x8 wr = __builtin_bit_cast(s16x8, bres[kt + 1]);
      a1 = __builtin_amdgcn_mfma_f32_16x16x32_bf16(ahh[0][kt + 1], wh, a1, 0, 0, 0);
      a1 = __builtin_amdgcn_mfma_f32_16x16x32_bf16(ahh[0][kt + 1], wr, a1, 0, 0, 0);
      a3 = __builtin_amdgcn_mfma_f32_16x16x32_bf16(ahh[1][kt + 1], wh, a3, 0, 0, 0);
      a3 = __builtin_amdgcn_mfma_f32_16x16x32_bf16(ahh[1][kt + 1], wr, a3, 0, 0, 0);
    }
    const f32x4 acc[2] = {a0 + a1, a2 + a3};

    // ---- elementwise cell update + stores (active lanes: c16 < BPG) ----
    if (active) {
      unsigned short* oHi = oHiBase + (size_t)bme * H_DIM;
      unsigned short* oRe = oReBase + (size_t)bme * H_DIM;
      #pragma unroll
      for (int rt = 0; rt < 2; ++rt) {
        const float gi = acc[rt][0] + bias[rt][0];
        const float gf = acc[rt][1] + bias[rt][1];
        const float gg = acc[rt][2] + bias[rt][2];
        const float go = acc[rt][3] + bias[rt][3];
        const float si = sigmoid_f(gi);
        const float sf = sigmoid_f(gf);
        const float so = sigmoid_f(go);
        const float cn = sf * creg[rt] + si * tanh_f(gg);
        const float hn = so * tanh_f(cn);
        const float hs = 0.5f * (hreg[rt] + hn);   // K = 0.5 leaky blend
        const float cs = 0.5f * (creg[rt] + cn);
        hreg[rt] = hs; creg[rt] = cs;
        out[((size_t)bme * T_STEPS + t) * H_DIM + jme[rt]] = hs;
        const unsigned short h16 = bf16_rne(hs);
        const unsigned short r16 = bf16_rne(hs - bf16_to_f(h16));
        st_mall_u16(oHi + jme[rt], h16);
        st_mall_u16(oRe + jme[rt], r16);
        if (t == T_STEPS - 1) {
          const size_t base2 = (size_t)B_TOT * T_STEPS * H_DIM;
          out[base2 + (size_t)bme * 1024 + jme[rt]] = hs;
          out[base2 + (size_t)bme * 1024 + H_DIM + jme[rt]] = cs;
        }
      }
    }

    // ---- announce: drain this wave's stores, then flag = t+1 ----
    if (t < T_STEPS - 1) {
      asm volatile("s_waitcnt vmcnt(0)" ::: "memory");
      __builtin_amdgcn_sched_barrier(0);
      if (l == 0) st_mall_b32(myflag, (unsigned)(t + 1));
    }
  }
}

extern "C" void kernel_launch(void* const* d_in, const int* in_sizes, int n_in,
                              void* d_out, int out_size, void* d_ws, size_t ws_size,
                              hipStream_t stream) {
  (void)in_sizes; (void)n_in; (void)out_size; (void)ws_size;
  const float* x   = (const float*)d_in[0];
  const float* Wih = (const float*)d_in[1];
  const float* Whh = (const float*)d_in[2];
  const float* bih = (const float*)d_in[3];
  const float* bhh = (const float*)d_in[4];
  float* out = (float*)d_out;
  unsigned short* sHi  = (unsigned short*)d_ws;
  unsigned short* sRes = (unsigned short*)((char*)d_ws + SRES_OFF);
  unsigned* flags = (unsigned*)((char*)d_ws + FLAGS_OFF);

  // zero h0 state (both slots) and flags, every launch (graph-safe)
  hipMemsetAsync(d_ws, 0, WS_BYTES, stream);

  hipLaunchKernelGGL(stnrnn_kernel, dim3(NGROUP * WGS), dim3(NTH), 0,
                     stream, x, Wih, Whh, bih, bhh, out, sHi, sRes, flags);
}